// Round 1
// baseline (252.249 us; speedup 1.0000x reference)
//
#include <hip/hip_runtime.h>

// CHMM forward-backward with clone-structured deterministic emission.
// n_clones = 4096/512 = 8 -> alpha/gamma have support on 8 states per step.
// Entire FB pass = length-8191 recurrence over 8-dim vectors, solved with a
// 3-phase chunked scan. Gamma output is 128 MiB of zeros + 8 floats per row.

#define NSTATES 4096
#define NBLK    8
#define LSEQ    8192
#define NSTEPS  8191   // LSEQ-1
#define CHK     128    // steps per chunk
#define NCH     64     // number of chunks (64*128 = 8192 >= 8191)

// workspace layout (float offsets)
#define OFF_M   0u        // M[t*64 + j*8 + i]  = T[bt+i][bt1+j]  (col-major per step)
#define OFF_M2  524288u   // M2[t*64 + i*8 + j] = T[bt+i][bt1+j]  (row-major per step)
#define OFF_P   1048576u  // P[c*64 + j*8 + i]  = chunk product, row i col j
#define OFF_P2  1052672u  // P2[c*64 + i*8 + j]
#define OFF_AB  1056768u  // Ab[c*8+i] alpha at chunk start
#define OFF_BB  1057280u  // Bb[c*8+j] beta at chunk end
#define OFF_A   1057792u  // A[t*8+i] normalized alpha per step
// total 1123328 floats = ~4.3 MB

__global__ __launch_bounds__(256) void k_prep(const float* __restrict__ T,
                                              const int* __restrict__ obs,
                                              float* __restrict__ out,
                                              float* __restrict__ ws)
{
    int tid = blockIdx.x * blockDim.x + threadIdx.x;
    int nth = gridDim.x * blockDim.x;
    // zero-fill gamma (and out[0..3]) via float4
    float4* o4 = reinterpret_cast<float4*>(out);
    const float4 z = make_float4(0.f, 0.f, 0.f, 0.f);
    const int n4 = (LSEQ * NSTATES) / 4;  // 8388608 vec4 -> covers out[0..33554431]
    for (int idx = tid; idx < n4; idx += nth) o4[idx] = z;
    if (tid == 0) out[(size_t)LSEQ * NSTATES] = 0.f;  // last gamma element
    // gather 8x8 transition blocks for every step, in two layouts
    for (int e = tid; e < NSTEPS * 64; e += nth) {
        int t = e >> 6, r = e & 63, i = r >> 3, j = r & 7;
        int row = obs[t] * NBLK + i;
        int col = obs[t + 1] * NBLK + j;
        float v = T[(size_t)row * NSTATES + col];
        ws[OFF_M  + t * 64 + j * 8 + i] = v;
        ws[OFF_M2 + t * 64 + i * 8 + j] = v;
    }
}

// Phase 1: per-chunk 8x8 matrix products, renormalized per step.
// 8 lanes per chunk; lane holds row i of the running product.
__global__ __launch_bounds__(64) void k_chunkprod(float* __restrict__ ws)
{
    int lane = threadIdx.x;
    int i = lane & 7;
    int c = blockIdx.x * 8 + (lane >> 3);
    int t0 = c * CHK;
    int te = min(t0 + CHK, NSTEPS);
    const float* M2 = ws + OFF_M2;
    float p[8];
#pragma unroll
    for (int j = 0; j < 8; ++j) p[j] = M2[t0 * 64 + i * 8 + j];
    for (int t = t0 + 1; t < te; ++t) {
        float m[64];
        const float4* mt = reinterpret_cast<const float4*>(M2 + t * 64);
#pragma unroll
        for (int q = 0; q < 16; ++q) reinterpret_cast<float4*>(m)[q] = mt[q];
        float pn[8];
#pragma unroll
        for (int j = 0; j < 8; ++j) {
            float s = p[0] * m[0 * 8 + j];
#pragma unroll
            for (int k = 1; k < 8; ++k) s = fmaf(p[k], m[k * 8 + j], s);
            pn[j] = s;
        }
        float rs = ((pn[0] + pn[1]) + (pn[2] + pn[3])) + ((pn[4] + pn[5]) + (pn[6] + pn[7]));
        rs += __shfl_xor(rs, 1);
        rs += __shfl_xor(rs, 2);
        rs += __shfl_xor(rs, 4);
        float sc = 1.0f / rs;
#pragma unroll
        for (int j = 0; j < 8; ++j) p[j] = pn[j] * sc;
    }
#pragma unroll
    for (int j = 0; j < 8; ++j) {
        ws[OFF_P  + c * 64 + j * 8 + i] = p[j];
        ws[OFF_P2 + c * 64 + i * 8 + j] = p[j];
    }
}

// Phase 2: single-wave sequential scan over chunk boundaries (fwd then bwd).
__global__ __launch_bounds__(64) void k_boundary(const float* __restrict__ Pi,
                                                 const int* __restrict__ obs,
                                                 float* __restrict__ out,
                                                 float* __restrict__ ws)
{
    int lane = threadIdx.x;
    int j = lane & 7;
    // alpha0
    int o0 = obs[0];
    float a[8];
    float c0 = 0.f;
#pragma unroll
    for (int i = 0; i < 8; ++i) { a[i] = Pi[o0 * NBLK + i]; c0 += a[i]; }
    float rc0 = 1.0f / c0;
#pragma unroll
    for (int i = 0; i < 8; ++i) a[i] *= rc0;
    if (lane == 0) {
        out[0] = __logf(c0);
#pragma unroll
        for (int i = 0; i < 8; ++i) { ws[OFF_A + i] = a[i]; ws[OFF_AB + i] = a[i]; }
    }
    // forward over chunks: Ab[c+1] = normalize(Ab[c] @ P_c)
    for (int c = 0; c < NCH - 1; ++c) {
        const float* pc = ws + OFF_P + c * 64 + j * 8;
        float u = 0.f;
#pragma unroll
        for (int i = 0; i < 8; ++i) u = fmaf(a[i], pc[i], u);
        float s = 0.f;
#pragma unroll
        for (int i = 0; i < 8; ++i) { float x = __shfl(u, i, 8); a[i] = x; s += x; }
        float rc = 1.0f / s;
#pragma unroll
        for (int i = 0; i < 8; ++i) a[i] *= rc;
        if (lane == 0) {
#pragma unroll
            for (int i = 0; i < 8; ++i) ws[OFF_AB + (c + 1) * 8 + i] = a[i];
        }
    }
    // backward over chunks: Bb[c-1] = normalize(P_c @ Bb[c]);  Bb[NCH-1] = const
    float w[8];
#pragma unroll
    for (int q = 0; q < 8; ++q) w[q] = 0.125f;
    if (lane == 0) {
#pragma unroll
        for (int q = 0; q < 8; ++q) ws[OFF_BB + (NCH - 1) * 8 + q] = w[q];
    }
    for (int c = NCH - 1; c >= 1; --c) {
        const float* pc = ws + OFF_P2 + c * 64 + j * 8;  // row j of P_c
        float u = 0.f;
#pragma unroll
        for (int q = 0; q < 8; ++q) u = fmaf(pc[q], w[q], u);
        float s = 0.f;
#pragma unroll
        for (int q = 0; q < 8; ++q) { float x = __shfl(u, q, 8); w[q] = x; s += x; }
        float rc = 1.0f / s;
#pragma unroll
        for (int q = 0; q < 8; ++q) w[q] *= rc;
        if (lane == 0) {
#pragma unroll
            for (int q = 0; q < 8; ++q) ws[OFF_BB + (c - 1) * 8 + q] = w[q];
        }
    }
}

// Phase 3 forward: within-chunk re-scan; emits per-step alpha + log(c) partials.
__global__ __launch_bounds__(64) void k_fwd(float* __restrict__ out,
                                            float* __restrict__ ws)
{
    int lane = threadIdx.x;
    int j = lane & 7;
    int c = blockIdx.x * 8 + (lane >> 3);
    int t0 = c * CHK;
    int te = min(t0 + CHK, NSTEPS);
    float a[8];
#pragma unroll
    for (int i = 0; i < 8; ++i) a[i] = ws[OFF_AB + c * 8 + i];
    float ll = 0.f;
    for (int t = t0; t < te; ++t) {
        const float4* mc = reinterpret_cast<const float4*>(ws + OFF_M + t * 64 + j * 8);
        float m[8];
        reinterpret_cast<float4*>(m)[0] = mc[0];
        reinterpret_cast<float4*>(m)[1] = mc[1];
        float u = a[0] * m[0];
#pragma unroll
        for (int i = 1; i < 8; ++i) u = fmaf(a[i], m[i], u);
        float s = 0.f;
#pragma unroll
        for (int i = 0; i < 8; ++i) { float x = __shfl(u, i, 8); a[i] = x; s += x; }
        float rc = 1.0f / s;
#pragma unroll
        for (int i = 0; i < 8; ++i) a[i] *= rc;
        ws[OFF_A + (t + 1) * 8 + j] = u * rc;
        ll += __logf(s);  // s == c_{t+1}
    }
    if (j == 0) atomicAdd(out, ll);
}

// Phase 3 backward: within-chunk beta re-scan + gamma scatter.
__global__ __launch_bounds__(64) void k_bwd(const int* __restrict__ obs,
                                            float* __restrict__ out,
                                            float* __restrict__ ws)
{
    int lane = threadIdx.x;
    int i = lane & 7;
    int c = blockIdx.x * 8 + (lane >> 3);
    int t0 = c * CHK;
    int te = min(t0 + CHK, NSTEPS);
    float* gamma = out + 1;
    float w[8];
#pragma unroll
    for (int q = 0; q < 8; ++q) w[q] = ws[OFF_BB + c * 8 + q];
    if (c == NCH - 1) {
        // gamma row L-1 = normalized alpha (beta = ones)
        float av = ws[OFF_A + (LSEQ - 1) * 8 + i];
        gamma[(size_t)(LSEQ - 1) * NSTATES + obs[LSEQ - 1] * NBLK + i] = av;
    }
    for (int t = te - 1; t >= t0; --t) {
        const float4* mr = reinterpret_cast<const float4*>(ws + OFF_M2 + t * 64 + i * 8);
        float m[8];
        reinterpret_cast<float4*>(m)[0] = mr[0];
        reinterpret_cast<float4*>(m)[1] = mr[1];
        float b = m[0] * w[0];
#pragma unroll
        for (int q = 1; q < 8; ++q) b = fmaf(m[q], w[q], b);
        // gamma_t[i] = alpha_t[i]*beta_t[i] / sum  (beta scale cancels)
        float av = ws[OFF_A + t * 8 + i];
        float gp = av * b;
        float gs = gp;
        gs += __shfl_xor(gs, 1);
        gs += __shfl_xor(gs, 2);
        gs += __shfl_xor(gs, 4);
        gamma[(size_t)t * NSTATES + obs[t] * NBLK + i] = gp / gs;
        // w <- normalize(beta_t) broadcast to all lanes of the group
        float s = 0.f;
#pragma unroll
        for (int q = 0; q < 8; ++q) { float x = __shfl(b, q, 8); w[q] = x; s += x; }
        float rc = 1.0f / s;
#pragma unroll
        for (int q = 0; q < 8; ++q) w[q] *= rc;
    }
}

extern "C" void kernel_launch(void* const* d_in, const int* in_sizes, int n_in,
                              void* d_out, int out_size, void* d_ws, size_t ws_size,
                              hipStream_t stream)
{
    const float* T   = (const float*)d_in[0];
    const float* Pi  = (const float*)d_in[1];
    const int*   obs = (const int*)d_in[2];
    float* out = (float*)d_out;
    float* ws  = (float*)d_ws;

    k_prep<<<2048, 256, 0, stream>>>(T, obs, out, ws);
    k_chunkprod<<<NCH / 8, 64, 0, stream>>>(ws);
    k_boundary<<<1, 64, 0, stream>>>(Pi, obs, out, ws);
    k_fwd<<<NCH / 8, 64, 0, stream>>>(out, ws);
    k_bwd<<<NCH / 8, 64, 0, stream>>>(obs, out, ws);
}

// Round 2
// 128.878 us; speedup vs baseline: 1.9573x; 1.9573x over previous
//
#include <hip/hip_runtime.h>

// CHMM forward-backward, clone-structured deterministic emission.
// n_clones = 4096/512 = 8 -> the whole FB pass is a length-8191 recurrence
// over 8-dim vectors. 3-phase chunked scan (NCH=128 chunks x CHK=64 steps),
// all serial scans run from LDS with register prefetch. Output = 128 MiB
// written exactly once by a streaming emit kernel (write-BW roofline ~21us).

#define NSTATES 4096
#define NBLK    8
#define LSEQ    8192
#define NSTEPS  8191
#define CHK     64
#define NCH     128

// workspace layout (float offsets)
#define OFF_M   0u        // M[t*64 + j*8 + i]  col-major per step (for fwd)
#define OFF_M2  524288u   // M2[t*64 + i*8 + j] row-major per step (for bwd/prod)
#define OFF_P   1048576u  // P[c*64 + j*8 + i]  chunk product col-major
#define OFF_P2  1056768u  // P2[c*64 + i*8 + j] chunk product row-major
#define OFF_AB  1064960u  // Ab[c*8+i] alpha at chunk start (normalized)
#define OFF_BB  1065984u  // Bb[c*8+j] beta at chunk end (arbitrary scale)
#define OFF_G   1067008u  // G[t*8+i]  normalized gamma, compact (8192*8)
#define OFF_LL0 1132544u  // log(c0)
#define OFF_LLP 1132545u  // per-chunk log-lik partials (128)

// KA: gather this chunk's 8x8 T-blocks (T -> LDS + ws in both layouts), then
// full-wave chunk product: lane (i,j) holds P[i][j]; 8 shfl+fma per step.
__global__ __launch_bounds__(64) void kA(const float* __restrict__ T,
                                         const int* __restrict__ obs,
                                         float* __restrict__ ws)
{
    __shared__ float sM2[CHK * 64];
    const int tid = threadIdx.x;
    const int c = blockIdx.x;
    const int t0 = c * CHK;
    const int te = min(t0 + CHK, NSTEPS);
    const int n = te - t0;

    for (int u = tid; u < n * 8; u += 64) {
        int dt = u >> 3, i = u & 7;
        int t = t0 + dt;
        int row = obs[t] * NBLK + i;
        int col = obs[t + 1] * NBLK;
        const float4* src = reinterpret_cast<const float4*>(T + (size_t)row * NSTATES + col);
        float4 v0 = src[0], v1 = src[1];
        float4* lp = reinterpret_cast<float4*>(&sM2[dt * 64 + i * 8]);
        lp[0] = v0; lp[1] = v1;
        float4* gr = reinterpret_cast<float4*>(ws + OFF_M2 + (size_t)t * 64 + i * 8);
        gr[0] = v0; gr[1] = v1;
        float vv[8] = {v0.x, v0.y, v0.z, v0.w, v1.x, v1.y, v1.z, v1.w};
        float* gm = ws + OFF_M + (size_t)t * 64;
#pragma unroll
        for (int j = 0; j < 8; ++j) gm[j * 8 + i] = vv[j];
    }
    __syncthreads();

    const int i = tid >> 3, j = tid & 7;
    float p = sM2[tid];  // P = M_{t0}; row-major [i*8+j] == tid
    float m[8], mn[8];
#pragma unroll
    for (int k = 0; k < 8; ++k) m[k] = sM2[64 + k * 8 + j];
    for (int dt = 1; dt < n; ++dt) {
        int dtn = min(dt + 1, n - 1);
#pragma unroll
        for (int k = 0; k < 8; ++k) mn[k] = sM2[dtn * 64 + k * 8 + j];  // prefetch
        float pn = 0.f;
#pragma unroll
        for (int k = 0; k < 8; ++k) pn = fmaf(__shfl(p, i * 8 + k, 64), m[k], pn);
        if ((dt & 3) == 0) {  // renormalize every 4th step (scale is arbitrary)
            float rs = pn;
            rs += __shfl_xor(rs, 1);  rs += __shfl_xor(rs, 2);
            rs += __shfl_xor(rs, 4);  rs += __shfl_xor(rs, 8);
            rs += __shfl_xor(rs, 16); rs += __shfl_xor(rs, 32);
            pn = pn / rs;
        }
        p = pn;
#pragma unroll
        for (int k = 0; k < 8; ++k) m[k] = mn[k];
    }
    ws[OFF_P  + c * 64 + j * 8 + i] = p;
    ws[OFF_P2 + c * 64 + tid] = p;
}

// KB: chunk-boundary scans. Wave 0 lanes 0-7: forward alpha boundaries.
// Wave 1 lanes 0-7: backward beta boundaries. Both from LDS, concurrent.
__global__ __launch_bounds__(128) void kB(const float* __restrict__ Pi,
                                          const int* __restrict__ obs,
                                          float* __restrict__ ws)
{
    __shared__ float sP[NCH * 64];
    __shared__ float sP2[NCH * 64];
    const int tid = threadIdx.x;
    {
        const float4* gp  = reinterpret_cast<const float4*>(ws + OFF_P);
        const float4* gp2 = reinterpret_cast<const float4*>(ws + OFF_P2);
        for (int q = tid; q < NCH * 16; q += 128) {
            reinterpret_cast<float4*>(sP)[q]  = gp[q];
            reinterpret_cast<float4*>(sP2)[q] = gp2[q];
        }
    }
    __syncthreads();

    if (tid < 8) {
        const int j = tid;
        float pj = Pi[obs[0] * NBLK + j];
        float c0 = pj;
        c0 += __shfl_xor(c0, 1); c0 += __shfl_xor(c0, 2); c0 += __shfl_xor(c0, 4);
        float rc0 = 1.0f / c0;
        float a[8];
#pragma unroll
        for (int q = 0; q < 8; ++q) a[q] = __shfl(pj, q, 8) * rc0;
        ws[OFF_AB + j] = a[j];
        if (j == 0) ws[OFF_LL0] = __logf(c0);
        float4 plo = *reinterpret_cast<const float4*>(&sP[j * 8]);
        float4 phi = *reinterpret_cast<const float4*>(&sP[j * 8 + 4]);
        for (int c = 0; c < NCH - 1; ++c) {
            int cn = c + 1;  // <= NCH-1: in bounds
            float4 nlo = *reinterpret_cast<const float4*>(&sP[cn * 64 + j * 8]);
            float4 nhi = *reinterpret_cast<const float4*>(&sP[cn * 64 + j * 8 + 4]);
            float u = a[0] * plo.x;
            u = fmaf(a[1], plo.y, u); u = fmaf(a[2], plo.z, u); u = fmaf(a[3], plo.w, u);
            u = fmaf(a[4], phi.x, u); u = fmaf(a[5], phi.y, u);
            u = fmaf(a[6], phi.z, u); u = fmaf(a[7], phi.w, u);
            float s = 0.f;
#pragma unroll
            for (int q = 0; q < 8; ++q) { float x = __shfl(u, q, 8); a[q] = x; s += x; }
            float rc = 1.0f / s;
#pragma unroll
            for (int q = 0; q < 8; ++q) a[q] *= rc;
            ws[OFF_AB + (c + 1) * 8 + j] = a[j];
            plo = nlo; phi = nhi;
        }
    } else if (tid >= 64 && tid < 72) {
        const int j = tid - 64;
        float w[8];
#pragma unroll
        for (int q = 0; q < 8; ++q) w[q] = 0.125f;
        ws[OFF_BB + (NCH - 1) * 8 + j] = 0.125f;
        float4 plo = *reinterpret_cast<const float4*>(&sP2[(NCH - 1) * 64 + j * 8]);
        float4 phi = *reinterpret_cast<const float4*>(&sP2[(NCH - 1) * 64 + j * 8 + 4]);
        for (int c = NCH - 1; c >= 1; --c) {
            int cn = c - 1;  // >= 0
            float4 nlo = *reinterpret_cast<const float4*>(&sP2[cn * 64 + j * 8]);
            float4 nhi = *reinterpret_cast<const float4*>(&sP2[cn * 64 + j * 8 + 4]);
            float u = w[0] * plo.x;
            u = fmaf(w[1], plo.y, u); u = fmaf(w[2], plo.z, u); u = fmaf(w[3], plo.w, u);
            u = fmaf(w[4], phi.x, u); u = fmaf(w[5], phi.y, u);
            u = fmaf(w[6], phi.z, u); u = fmaf(w[7], phi.w, u);
            float s = 0.f;
#pragma unroll
            for (int q = 0; q < 8; ++q) { float x = __shfl(u, q, 8); w[q] = x; s += x; }
            float rc = 1.0f / s;
#pragma unroll
            for (int q = 0; q < 8; ++q) w[q] *= rc;
            ws[OFF_BB + (c - 1) * 8 + j] = w[j];
            plo = nlo; phi = nhi;
        }
    }
}

// KC: per-chunk fwd re-scan (alpha history in LDS, log-lik partial) then
// bwd beta re-scan producing compact normalized gamma (8 floats/row).
__global__ __launch_bounds__(64) void kC(const int* __restrict__ obs,
                                         float* __restrict__ ws)
{
    __shared__ float sMc[CHK * 64];
    __shared__ float sMr[CHK * 64];
    __shared__ float sA[(CHK + 1) * 8];
    const int tid = threadIdx.x;
    const int c = blockIdx.x;
    const int t0 = c * CHK;
    const int te = min(t0 + CHK, NSTEPS);
    const int n = te - t0;
    {
        const float4* gc = reinterpret_cast<const float4*>(ws + OFF_M  + (size_t)t0 * 64);
        const float4* gr = reinterpret_cast<const float4*>(ws + OFF_M2 + (size_t)t0 * 64);
        for (int q = tid; q < n * 16; q += 64) {
            reinterpret_cast<float4*>(sMc)[q] = gc[q];
            reinterpret_cast<float4*>(sMr)[q] = gr[q];
        }
    }
    __syncthreads();

    if (tid < 8) {  // forward
        const int j = tid;
        float a[8];
#pragma unroll
        for (int q = 0; q < 8; ++q) a[q] = ws[OFF_AB + c * 8 + q];
        sA[j] = a[j];
        float ll = 0.f;
        float4 mlo = *reinterpret_cast<const float4*>(&sMc[j * 8]);
        float4 mhi = *reinterpret_cast<const float4*>(&sMc[j * 8 + 4]);
        for (int dt = 0; dt < n; ++dt) {
            int dn = min(dt + 1, n - 1);
            float4 nlo = *reinterpret_cast<const float4*>(&sMc[dn * 64 + j * 8]);
            float4 nhi = *reinterpret_cast<const float4*>(&sMc[dn * 64 + j * 8 + 4]);
            float u = a[0] * mlo.x;
            u = fmaf(a[1], mlo.y, u); u = fmaf(a[2], mlo.z, u); u = fmaf(a[3], mlo.w, u);
            u = fmaf(a[4], mhi.x, u); u = fmaf(a[5], mhi.y, u);
            u = fmaf(a[6], mhi.z, u); u = fmaf(a[7], mhi.w, u);
            float s = 0.f;
            float an[8];
#pragma unroll
            for (int q = 0; q < 8; ++q) { float x = __shfl(u, q, 8); an[q] = x; s += x; }
            float rc = 1.0f / s;   // s == true c_{t+1} (a was exactly normalized)
#pragma unroll
            for (int q = 0; q < 8; ++q) a[q] = an[q] * rc;
            sA[(dt + 1) * 8 + j] = a[j];
            ll += __logf(s);
            mlo = nlo; mhi = nhi;
        }
        if (j == 0) ws[OFF_LLP + c] = ll;
    }
    __syncthreads();
    if (tid < 8) {  // backward + gamma
        const int i = tid;
        float w[8];
#pragma unroll
        for (int q = 0; q < 8; ++q) w[q] = ws[OFF_BB + c * 8 + q];
        if (c == NCH - 1)  // row L-1: beta = const -> gamma = alpha
            ws[OFF_G + (size_t)(LSEQ - 1) * 8 + i] = sA[n * 8 + i];
        float4 mlo = *reinterpret_cast<const float4*>(&sMr[(n - 1) * 64 + i * 8]);
        float4 mhi = *reinterpret_cast<const float4*>(&sMr[(n - 1) * 64 + i * 8 + 4]);
        for (int dt = n - 1; dt >= 0; --dt) {
            int dn = max(dt - 1, 0);
            float4 nlo = *reinterpret_cast<const float4*>(&sMr[dn * 64 + i * 8]);
            float4 nhi = *reinterpret_cast<const float4*>(&sMr[dn * 64 + i * 8 + 4]);
            float b = w[0] * mlo.x;
            b = fmaf(w[1], mlo.y, b); b = fmaf(w[2], mlo.z, b); b = fmaf(w[3], mlo.w, b);
            b = fmaf(w[4], mhi.x, b); b = fmaf(w[5], mhi.y, b);
            b = fmaf(w[6], mhi.z, b); b = fmaf(w[7], mhi.w, b);
            float av = sA[dt * 8 + i];
            float gp = av * b;
            float gs = gp;
            gs += __shfl_xor(gs, 1); gs += __shfl_xor(gs, 2); gs += __shfl_xor(gs, 4);
            ws[OFF_G + (size_t)(t0 + dt) * 8 + i] = gp / gs;
            float sw = 0.f;
            float wn[8];
#pragma unroll
            for (int q = 0; q < 8; ++q) { float x = __shfl(b, q, 8); wn[q] = x; sw += x; }
            float rcw = 1.0f / sw;  // arbitrary scale
#pragma unroll
            for (int q = 0; q < 8; ++q) w[q] = wn[q] * rcw;
            mlo = nlo; mhi = nhi;
        }
    }
}

// KD: stream the full output once: out[0]=loglik, gamma row t = zeros with
// G[t] at cols [8*obs[t], 8*obs[t]+8). Coalesced float4 stores, write-BW bound.
__global__ __launch_bounds__(256) void kD(const int* __restrict__ obs,
                                          float* __restrict__ out,
                                          const float* __restrict__ ws)
{
    const int tid = blockIdx.x * 256 + threadIdx.x;
    const int nth = gridDim.x * 256;
    const int NB4 = (LSEQ * NSTATES) / 4;  // covers out[0..33554431]
    for (int k = tid; k < NB4; k += nth) {
        float v[4];
#pragma unroll
        for (int e = 0; e < 4; ++e) {
            int g = 4 * k + e - 1;          // gamma flat index (g==-1 only at out[0])
            g = g < 0 ? 0 : g;              // out[0] fixed up below by tid 0
            int t = g >> 12;
            int col = g & (NSTATES - 1);
            int d = col - obs[t] * NBLK;
            v[e] = ((unsigned)d < 8u) ? ws[OFF_G + (size_t)t * 8 + d] : 0.0f;
        }
        reinterpret_cast<float4*>(out)[k] = make_float4(v[0], v[1], v[2], v[3]);
    }
    if (tid == 0) {
        float ll = ws[OFF_LL0];
        for (int c = 0; c < NCH; ++c) ll += ws[OFF_LLP + c];  // deterministic
        out[0] = ll;  // same thread wrote out4[0] above: program order holds
        int d = (NSTATES - 1) - obs[LSEQ - 1] * NBLK;
        out[(size_t)LSEQ * NSTATES] =
            ((unsigned)d < 8u) ? ws[OFF_G + (size_t)(LSEQ - 1) * 8 + d] : 0.0f;
    }
}

extern "C" void kernel_launch(void* const* d_in, const int* in_sizes, int n_in,
                              void* d_out, int out_size, void* d_ws, size_t ws_size,
                              hipStream_t stream)
{
    const float* T   = (const float*)d_in[0];
    const float* Pi  = (const float*)d_in[1];
    const int*   obs = (const int*)d_in[2];
    float* out = (float*)d_out;
    float* ws  = (float*)d_ws;

    kA<<<NCH, 64, 0, stream>>>(T, obs, ws);
    kB<<<1, 128, 0, stream>>>(Pi, obs, ws);
    kC<<<NCH, 64, 0, stream>>>(obs, ws);
    kD<<<2048, 256, 0, stream>>>(obs, out, ws);
}

// Round 3
// 65.910 us; speedup vs baseline: 3.8272x; 1.9554x over previous
//
#include <hip/hip_runtime.h>

// CHMM forward-backward, clone-structured deterministic emission.
// n_clones = 8 -> FB pass = length-8191 recurrence over 8-dim vectors.
// 3-phase chunked scan, NCH=256 chunks x CHK=32 steps.
//  kA: blocks 0..255 gather T-blocks + chunk 8x8 products; blocks 256..2303
//      zero-fill the 128MiB output concurrently (BW-bound, hides the scan).
//  kB: 1 block: hierarchical boundary scan (16 group products -> dual group
//      scan -> within-group fill-in), fwd+bwd branchless in the same wave.
//  kC: per-chunk dual re-scan (fwd lanes 0-7, bwd lanes 8-15, one instruction
//      stream) + gamma scatter directly into the pre-zeroed output.

#define NSTATES 4096
#define NBLK    8
#define LSEQ    8192
#define NSTEPS  8191
#define CHK     32
#define NCH     256     // NCH*CHK = 8192 >= NSTEPS
#define NGRP    16
#define GSZ     16      // chunks per group
#define FILLB   2048    // fill blocks in kA

// workspace layout (float offsets)
#define OFF_M   0u        // M[t*64 + j*8 + i] col-major per step (2MB)
#define OFF_P   524288u   // P[c*64 + j*8 + i] chunk products col-major
#define OFF_AB  540672u   // Ab[c*8+i] alpha at chunk start (normalized)
#define OFF_BB  542720u   // Bb[c*8+j] beta at chunk end (normalized)

__device__ __forceinline__ float exp_renorm(float x, float ref) {
    int k = (int)((__float_as_uint(ref) >> 23) & 0xff) - 127;
    return ldexpf(x, -k);
}

__global__ __launch_bounds__(256) void kA(const float* __restrict__ T,
                                          const int* __restrict__ obs,
                                          float* __restrict__ out,
                                          float* __restrict__ ws)
{
    const int b = blockIdx.x;
    const int tid = threadIdx.x;
    if (b >= NCH) {
        // zero-fill out[0 .. LSEQ*NSTATES] (129 MB region, coalesced float4)
        const int fb = b - NCH;
        float4* o4 = reinterpret_cast<float4*>(out);
        const float4 z = make_float4(0.f, 0.f, 0.f, 0.f);
        int idx = fb * 256 + tid;
#pragma unroll
        for (int it = 0; it < 16; ++it) {
            o4[idx] = z;             // 16 * FILLB * 256 = 8388608 float4 exactly
            idx += FILLB * 256;
        }
        if (fb == 0 && tid == 0) out[(size_t)LSEQ * NSTATES] = 0.f;
        return;
    }
    // ---- chunk block ----
    __shared__ float sM2[CHK * 64];              // row-major per step
    const int c = b, t0 = c * CHK;
    const int n = min(CHK, NSTEPS - t0);         // 32, last chunk 31
    {
        int dt = tid >> 3, i = tid & 7;
        if (dt < n) {
            int t = t0 + dt;
            int row = obs[t] * NBLK + i;
            int col = obs[t + 1] * NBLK;
            const float4* src = reinterpret_cast<const float4*>(T + (size_t)row * NSTATES + col);
            float4 v0 = src[0], v1 = src[1];
            float4* lp = reinterpret_cast<float4*>(&sM2[dt * 64 + i * 8]);
            lp[0] = v0; lp[1] = v1;
            float vv[8] = {v0.x, v0.y, v0.z, v0.w, v1.x, v1.y, v1.z, v1.w};
            float* gm = ws + OFF_M + (size_t)t * 64;   // col-major for kC
#pragma unroll
            for (int q = 0; q < 8; ++q) gm[q * 8 + i] = vv[q];
        }
    }
    __syncthreads();
    if (tid < 64) {
        const int i = tid >> 3, j = tid & 7;
        float p = sM2[i * 8 + j];
        float m[8], mn[8];
#pragma unroll
        for (int k = 0; k < 8; ++k) m[k] = sM2[64 + k * 8 + j];
        for (int dt = 1; dt < n; ++dt) {
            int dtn = min(dt + 1, n - 1);
#pragma unroll
            for (int k = 0; k < 8; ++k) mn[k] = sM2[dtn * 64 + k * 8 + j];
            float pn = 0.f;
#pragma unroll
            for (int k = 0; k < 8; ++k) pn = fmaf(__shfl(p, i * 8 + k, 64), m[k], pn);
            if ((dt & 3) == 0) pn = exp_renorm(pn, __shfl(pn, 0, 64));
            p = pn;
#pragma unroll
            for (int k = 0; k < 8; ++k) m[k] = mn[k];
        }
        p = exp_renorm(p, __shfl(p, 0, 64));
        ws[OFF_P + c * 64 + j * 8 + i] = p;      // col-major
    }
}

__global__ __launch_bounds__(1024) void kB(const float* __restrict__ Pi,
                                           const int* __restrict__ obs,
                                           float* __restrict__ out,
                                           float* __restrict__ ws)
{
    __shared__ float sG[NGRP * 64];              // group products, col-major
    __shared__ float sAG[NGRP * 8], sBG[NGRP * 8];
    const int tid = threadIdx.x;
    const int w = tid >> 6, lane = tid & 63;
    // step1: wave w computes G_w = P_{16w} @ ... @ P_{16w+15}
    {
        const int i = lane >> 3, j = lane & 7;
        const float* Pg = ws + OFF_P;
        float p = Pg[(GSZ * w) * 64 + j * 8 + i];
        float4 c0 = *reinterpret_cast<const float4*>(&Pg[(GSZ * w + 1) * 64 + j * 8]);
        float4 c1 = *reinterpret_cast<const float4*>(&Pg[(GSZ * w + 1) * 64 + j * 8 + 4]);
        for (int r = 1; r < GSZ; ++r) {
            int rn = min(r + 1, GSZ - 1);
            float4 n0 = *reinterpret_cast<const float4*>(&Pg[(GSZ * w + rn) * 64 + j * 8]);
            float4 n1 = *reinterpret_cast<const float4*>(&Pg[(GSZ * w + rn) * 64 + j * 8 + 4]);
            float m[8] = {c0.x, c0.y, c0.z, c0.w, c1.x, c1.y, c1.z, c1.w};
            float pn = 0.f;
#pragma unroll
            for (int k = 0; k < 8; ++k) pn = fmaf(__shfl(p, i * 8 + k, 64), m[k], pn);
            if ((r & 1) == 0 || r == GSZ - 1) pn = exp_renorm(pn, __shfl(pn, 0, 64));
            p = pn;
            c0 = n0; c1 = n1;
        }
        sG[w * 64 + j * 8 + i] = p;
    }
    __syncthreads();
    // step2: wave 0 lanes 0-15: fwd group scan (lanes 0-7), bwd (lanes 8-15),
    // one branchless instruction stream.
    if (tid < 16) {
        const int grp = tid >> 3, l8 = tid & 7;
        float v[8];
        int o0 = obs[0];
        float a = Pi[o0 * NBLK + l8];
        float s0 = a;
        s0 += __shfl_xor(s0, 1); s0 += __shfl_xor(s0, 2); s0 += __shfl_xor(s0, 4);
        float rs0 = 1.0f / s0;
#pragma unroll
        for (int q = 0; q < 8; ++q) v[q] = grp ? 0.125f : __shfl(a, q, 8) * rs0;
        if (tid == 0) out[0] = __logf(s0);       // ll0; kC atomicAdds the rest
        float* dst0 = grp ? &sBG[(NGRP - 1) * 8] : &sAG[0];
        dst0[l8] = v[l8];
        for (int r = 0; r < NGRP - 1; ++r) {
            int gi = grp ? (NGRP - 1 - r) : r;
            const float* mb = &sG[gi * 64 + (grp ? l8 : l8 * 8)];
            int st = grp ? 8 : 1;
            float m[8];
#pragma unroll
            for (int q = 0; q < 8; ++q) m[q] = mb[q * st];
            float u = 0.f;
#pragma unroll
            for (int q = 0; q < 8; ++q) u = fmaf(v[q], m[q], u);
            float s = 0.f;
#pragma unroll
            for (int q = 0; q < 8; ++q) { float x = __shfl(u, q, 8); v[q] = x; s += x; }
            float rs = 1.0f / s;
#pragma unroll
            for (int q = 0; q < 8; ++q) v[q] *= rs;
            float* dst = grp ? &sBG[(NGRP - 2 - r) * 8] : &sAG[(r + 1) * 8];
            dst[l8] = v[l8];
        }
    }
    __syncthreads();
    // step3: wave w: fwd over chunks 16w..16w+14 (lanes 0-7),
    //                bwd over chunks 16w+15..16w+1 (lanes 8-15), branchless.
    if (lane < 16) {
        const int grp = lane >> 3, l8 = lane & 7;
        float v[8];
#pragma unroll
        for (int q = 0; q < 8; ++q) v[q] = grp ? sBG[w * 8 + q] : sAG[w * 8 + q];
        unsigned i0 = grp ? (OFF_BB + (GSZ * w + GSZ - 1) * 8 + l8)
                          : (OFF_AB + (GSZ * w) * 8 + l8);
        ws[i0] = v[l8];
        const float* base = ws + OFF_P;
        int st = grp ? 8 : 1;
        int boff = grp ? l8 : l8 * 8;
        int c0i = grp ? (GSZ * w + GSZ - 1) : (GSZ * w);
        float m[8], mn[8];
#pragma unroll
        for (int q = 0; q < 8; ++q) m[q] = base[c0i * 64 + boff + q * st];
        for (int r = 0; r < GSZ - 1; ++r) {
            int rp = min(r + 1, GSZ - 2);
            int cn = grp ? (GSZ * w + GSZ - 1 - rp) : (GSZ * w + rp);
#pragma unroll
            for (int q = 0; q < 8; ++q) mn[q] = base[cn * 64 + boff + q * st];
            float u = 0.f;
#pragma unroll
            for (int q = 0; q < 8; ++q) u = fmaf(v[q], m[q], u);
            float s = 0.f;
#pragma unroll
            for (int q = 0; q < 8; ++q) { float x = __shfl(u, q, 8); v[q] = x; s += x; }
            float rs = 1.0f / s;
#pragma unroll
            for (int q = 0; q < 8; ++q) v[q] *= rs;
            unsigned idx = grp ? (OFF_BB + (GSZ * w + GSZ - 2 - r) * 8 + l8)
                               : (OFF_AB + (GSZ * w + r + 1) * 8 + l8);
            ws[idx] = v[l8];
#pragma unroll
            for (int q = 0; q < 8; ++q) m[q] = mn[q];
        }
    }
}

__global__ __launch_bounds__(64) void kC(const int* __restrict__ obs,
                                         float* __restrict__ out,
                                         float* __restrict__ ws)
{
    __shared__ float sM[CHK * 64];
    __shared__ float sA[(CHK + 1) * 8], sB[(CHK + 1) * 8];
    __shared__ int sObs[CHK];
    const int tid = threadIdx.x;
    const int c = blockIdx.x, t0 = c * CHK;
    const int n = min(CHK, NSTEPS - t0);
    {
        const float4* g = reinterpret_cast<const float4*>(ws + OFF_M + (size_t)t0 * 64);
        float4* l = reinterpret_cast<float4*>(sM);
        for (int q = tid; q < n * 16; q += 64) l[q] = g[q];
        if (tid < CHK) sObs[tid] = obs[t0 + tid];
    }
    __syncthreads();
    if (tid < 16) {   // fwd lanes 0-7, bwd lanes 8-15, one instruction stream
        const int grp = tid >> 3, l8 = tid & 7;
        float v[8];
#pragma unroll
        for (int q = 0; q < 8; ++q)
            v[q] = grp ? ws[OFF_BB + c * 8 + q] : ws[OFF_AB + c * 8 + q];
        float* hist = grp ? sB : sA;
        hist[(grp ? n : 0) * 8 + l8] = v[l8];
        int st = grp ? 8 : 1;
        int boff = grp ? l8 : l8 * 8;
        int mt0 = grp ? (n - 1) : 0;
        float m[8], mn[8];
#pragma unroll
        for (int q = 0; q < 8; ++q) m[q] = sM[mt0 * 64 + boff + q * st];
        float ll = 0.f;
        for (int r = 0; r < n; ++r) {
            int rn = min(r + 1, n - 1);
            int mtn = grp ? (n - 1 - rn) : rn;
#pragma unroll
            for (int q = 0; q < 8; ++q) mn[q] = sM[mtn * 64 + boff + q * st];
            float u = 0.f;
#pragma unroll
            for (int q = 0; q < 8; ++q) u = fmaf(v[q], m[q], u);
            float s = 0.f;
#pragma unroll
            for (int q = 0; q < 8; ++q) { float x = __shfl(u, q, 8); v[q] = x; s += x; }
            float rs = 1.0f / s;
#pragma unroll
            for (int q = 0; q < 8; ++q) v[q] *= rs;
            hist[(grp ? (n - 1 - r) : (r + 1)) * 8 + l8] = v[l8];
            ll += __logf(s);
#pragma unroll
            for (int q = 0; q < 8; ++q) m[q] = mn[q];
        }
        if (tid == 0) atomicAdd(out, ll);
    }
    __syncthreads();
    {   // gamma: group g of 8 lanes handles rows g, g+8, g+16, g+24
        const int g = tid >> 3, i = tid & 7;
        float* gamma = out + 1;
#pragma unroll
        for (int rr0 = 0; rr0 < CHK; rr0 += 8) {
            int rr = rr0 + g;
            float gp = sA[rr * 8 + i] * sB[rr * 8 + i];
            float gs = gp;
            gs += __shfl_xor(gs, 1); gs += __shfl_xor(gs, 2); gs += __shfl_xor(gs, 4);
            int t = t0 + rr;
            gamma[(size_t)t * NSTATES + sObs[rr] * NBLK + i] = gp / gs;
        }
    }
}

extern "C" void kernel_launch(void* const* d_in, const int* in_sizes, int n_in,
                              void* d_out, int out_size, void* d_ws, size_t ws_size,
                              hipStream_t stream)
{
    const float* T   = (const float*)d_in[0];
    const float* Pi  = (const float*)d_in[1];
    const int*   obs = (const int*)d_in[2];
    float* out = (float*)d_out;
    float* ws  = (float*)d_ws;

    kA<<<NCH + FILLB, 256, 0, stream>>>(T, obs, out, ws);
    kB<<<1, 1024, 0, stream>>>(Pi, obs, out, ws);
    kC<<<NCH, 64, 0, stream>>>(obs, out, ws);
}